// Round 5
// baseline (114.092 us; speedup 1.0000x reference)
//
#include <hip/hip_runtime.h>

// MonotoneActivation: per (b,g) group of ARITY=4 inputs, sort-4, barycentric
// interpolation over the 2^4 lattice, OUT_DIM=4 outputs.
//
// R13 design = R11 exactly (two-kernel, 2 KiB mask table, 4 rows/block,
// 4 named load regs, loads-first) with ONE change: NORMAL stores (not nt).
//  - R12 post-mortem: 8-deep window at 2048 blocks = 113.2 vs R11's 110.8
//    -> no gain from deeper per-wave window; 4096-block config wins.
//  - nt-store rationale is obsolete in the loads-first structure: no load
//    ever waits behind a store in the vmcnt queue, so nt's only remaining
//    effect is forcing the 64 MiB write stream to HBM on the kernel's
//    critical path. Normal full-line wave stores (1 KiB/wave contiguous,
//    no RFO) land in L3 (just swept empty by the 256 MiB ws-poison) and
//    drain asynchronously under the harness's subsequent fills.
//  - Single-variable A/B vs R11: store instruction only.
//  - params is binary (0.0/1.0, corner 15 forced 1) -> 64-bit mask/group;
//    selection via (float)bit * coef is exact -> absmax 0.

#define GROUPS        256
#define ROWS_PER_BLK  4
#define BATCH         16384
#define NBLOCKS       (BATCH / ROWS_PER_BLK)   // 4096
#define BLOCK_T       256

typedef float f4 __attribute__((ext_vector_type(4)));

// ---- kernel 1: compress params [256][16][4] f32 -> 256 x u64 bitmasks ----
__global__ __launch_bounds__(256) void build_masks_kernel(
    const float* __restrict__ params,
    unsigned long long* __restrict__ masks)
{
    const int g = threadIdx.x;                 // one thread per group
    const f4* __restrict__ P = reinterpret_cast<const f4*>(params) + (g << 4);
    unsigned long long m = 0ull;
    #pragma unroll
    for (int e = 0; e < 16; ++e) {
        const f4 p = P[e];
        const unsigned long long nib =
            (unsigned long long)(p.x != 0.0f)
          | ((unsigned long long)(p.y != 0.0f) << 1)
          | ((unsigned long long)(p.z != 0.0f) << 2)
          | ((unsigned long long)(p.w != 0.0f) << 3);
        m |= nib << (4 * e);
    }
    masks[g] = m;
}

// ---- kernel 2: streaming compute, one group-column per thread ----
__global__ __launch_bounds__(BLOCK_T, 8) void mono_act_kernel(
    const float* __restrict__ X,
    const unsigned long long* __restrict__ masks,  // [256], 2 KiB, L2-hot
    float* __restrict__ out)                       // [BATCH, GROUPS*4]
{
    const int g  = threadIdx.x;                    // group == lane column
    const int r0 = blockIdx.x * ROWS_PER_BLK;

    const unsigned long long m = masks[g];

    const f4* __restrict__ X4 = reinterpret_cast<const f4*>(X) + g;
    f4* __restrict__ O4       = reinterpret_cast<f4*>(out) + g;

    const size_t base = (size_t)r0 * GROUPS;       // f4 units

    // ---- issue ALL row loads into NAMED registers (no array -> no scratch) ----
    const f4 x0 = X4[base];
    const f4 x1 = X4[base + GROUPS];
    const f4 x2 = X4[base + 2 * (size_t)GROUPS];
    const f4 x3 = X4[base + 3 * (size_t)GROUPS];

    // sort-4 network + barycentric blend; params bit-selected from mask m.
#define PROCESS(xv, off)                                                  \
    do {                                                                  \
        float a0 = (xv).x, a1 = (xv).y, a2 = (xv).z, a3 = (xv).w;         \
        int i0 = 1, i1 = 2, i2 = 4, i3 = 8;   /* 1 << original index */   \
        /* stable sorting network (strict >): (0,1)(2,3)(0,2)(1,3)(1,2) */\
        if (a0 > a1) { float t=a0;a0=a1;a1=t; int u=i0;i0=i1;i1=u; }      \
        if (a2 > a3) { float t=a2;a2=a3;a3=t; int u=i2;i2=i3;i3=u; }      \
        if (a0 > a2) { float t=a0;a0=a2;a2=t; int u=i0;i0=i2;i2=u; }      \
        if (a1 > a3) { float t=a1;a1=a3;a3=t; int u=i1;i1=i3;i3=u; }      \
        if (a1 > a2) { float t=a1;a1=a2;a2=t; int u=i1;i1=i2;i2=u; }      \
        const float c0 = a0;                                              \
        const float c1 = a1 - a0;                                         \
        const float c2 = a2 - a1;                                         \
        const float c3 = a3 - a2;                                         \
        const int e3 = i3;                                                \
        const int e2 = e3 | i2;                                           \
        const int e1 = e2 | i1;                                           \
        const unsigned int s1 = (unsigned int)(m >> (e1 << 2));           \
        const unsigned int s2 = (unsigned int)(m >> (e2 << 2));           \
        const unsigned int s3 = (unsigned int)(m >> (e3 << 2));           \
        f4 r;                                                             \
        r.x = c0 + c1 * (float)( s1       & 1)                            \
                 + c2 * (float)( s2       & 1)                            \
                 + c3 * (float)( s3       & 1);                           \
        r.y = c0 + c1 * (float)((s1 >> 1) & 1)                            \
                 + c2 * (float)((s2 >> 1) & 1)                            \
                 + c3 * (float)((s3 >> 1) & 1);                           \
        r.z = c0 + c1 * (float)((s1 >> 2) & 1)                            \
                 + c2 * (float)((s2 >> 2) & 1)                            \
                 + c3 * (float)((s3 >> 2) & 1);                           \
        r.w = c0 + c1 * (float)((s1 >> 3) & 1)                            \
                 + c2 * (float)((s2 >> 3) & 1)                            \
                 + c3 * (float)((s3 >> 3) & 1);                           \
        O4[(off)] = r;   /* NORMAL store: allocate in L3, drain async */  \
    } while (0)

    PROCESS(x0, base);
    PROCESS(x1, base + GROUPS);
    PROCESS(x2, base + 2 * (size_t)GROUPS);
    PROCESS(x3, base + 3 * (size_t)GROUPS);
#undef PROCESS
}

extern "C" void kernel_launch(void* const* d_in, const int* in_sizes, int n_in,
                              void* d_out, int out_size, void* d_ws, size_t ws_size,
                              hipStream_t stream) {
    const float* X      = (const float*)d_in[0];
    const float* params = (const float*)d_in[1];
    float* out          = (float*)d_out;
    unsigned long long* masks = (unsigned long long*)d_ws;  // 2 KiB scratch

    build_masks_kernel<<<1, 256, 0, stream>>>(params, masks);
    mono_act_kernel<<<NBLOCKS, BLOCK_T, 0, stream>>>(X, masks, out);
}

// Round 6
// 111.368 us; speedup vs baseline: 1.0245x; 1.0245x over previous
//
#include <hip/hip_runtime.h>

// MonotoneActivation: per (b,g) group of ARITY=4 inputs, sort-4, barycentric
// interpolation over the 2^4 lattice, OUT_DIM=4 outputs.
//
// R14 = FINAL = exact revert to R11, the session's verified best (110.8 us).
// Design: two-kernel (2 KiB mask table in d_ws) + 4 rows/block, 4 NAMED
// load registers, loads-first, non-temporal stores.
//
// Session A/B ledger (total dur_us; harness-owned resets ~77-80 of each):
//   R8  interleaved 8-row, nt, two-kernel ........ 115.3
//   R9  fused rebuild, 16-row .................... 120.0  (occupancy 30%)
//   R10 8-row f4 xv[8] array ..................... 179.4  (SPILLED to scratch)
//   R11 4-row, 4 named regs, loads-first, nt ..... 110.8  <= best
//   R12 8-row, 8 named regs, 2048 blocks ......... 113.2  (noise/slightly worse)
//   R13 R11 + normal stores ...................... 114.1  (noise/slightly worse)
// Exhausted axes: rows/block {4,8,16}, load-window {interleaved,4,8,array},
// store {nt,normal}, fusion {yes,no}. R11 is the unique minimum.
//
// Why this is the effective roofline:
//  - mono_act moves 128 MiB (64 read + 64 nt-write) in ~28 us ~= 4.5 TB/s
//    effective mixed r/w (vs 6.3 TB/s pure-stream ceiling); it no longer
//    appears in the top-5 counter rows.
//  - The measured iteration is dominated by harness resets: 256 MiB ws
//    poison (~42 us, fires even if d_ws is unused - proven in R9), 64 MiB
//    out poison (~11 us), X restore copy (~21 us), all at 78-82% of peak.
//  - Ideal total ~= 103-105 us; remaining ~6 us gap = mixed-stream plateau
//    + two-kernel launch bubble (fusion A/B'd: cost ~= benefit).
//
// Correctness: params is binary (0.0/1.0, corner 15 forced 1), so each
// group compresses to a 64-bit mask; selection via (float)bit * coef is
// exact -> absmax 0. Sorting network is stable (strict >), matching
// jnp.argsort; ties give coef 0 so tie-order cannot change the output.

#define GROUPS        256
#define ROWS_PER_BLK  4
#define BATCH         16384
#define NBLOCKS       (BATCH / ROWS_PER_BLK)   // 4096
#define BLOCK_T       256

typedef float f4 __attribute__((ext_vector_type(4)));

// ---- kernel 1: compress params [256][16][4] f32 -> 256 x u64 bitmasks ----
__global__ __launch_bounds__(256) void build_masks_kernel(
    const float* __restrict__ params,
    unsigned long long* __restrict__ masks)
{
    const int g = threadIdx.x;                 // one thread per group
    const f4* __restrict__ P = reinterpret_cast<const f4*>(params) + (g << 4);
    unsigned long long m = 0ull;
    #pragma unroll
    for (int e = 0; e < 16; ++e) {
        const f4 p = P[e];
        const unsigned long long nib =
            (unsigned long long)(p.x != 0.0f)
          | ((unsigned long long)(p.y != 0.0f) << 1)
          | ((unsigned long long)(p.z != 0.0f) << 2)
          | ((unsigned long long)(p.w != 0.0f) << 3);
        m |= nib << (4 * e);
    }
    masks[g] = m;
}

// ---- kernel 2: streaming compute, one group-column per thread ----
__global__ __launch_bounds__(BLOCK_T, 8) void mono_act_kernel(
    const float* __restrict__ X,
    const unsigned long long* __restrict__ masks,  // [256], 2 KiB, L2-hot
    float* __restrict__ out)                       // [BATCH, GROUPS*4]
{
    const int g  = threadIdx.x;                    // group == lane column
    const int r0 = blockIdx.x * ROWS_PER_BLK;

    const unsigned long long m = masks[g];

    const f4* __restrict__ X4 = reinterpret_cast<const f4*>(X) + g;
    f4* __restrict__ O4       = reinterpret_cast<f4*>(out) + g;

    const size_t base = (size_t)r0 * GROUPS;       // f4 units

    // ---- issue ALL row loads into NAMED registers (no array -> no scratch) ----
    const f4 x0 = X4[base];
    const f4 x1 = X4[base + GROUPS];
    const f4 x2 = X4[base + 2 * (size_t)GROUPS];
    const f4 x3 = X4[base + 3 * (size_t)GROUPS];

    // sort-4 network + barycentric blend; params bit-selected from mask m.
#define PROCESS(xv, off)                                                  \
    do {                                                                  \
        float a0 = (xv).x, a1 = (xv).y, a2 = (xv).z, a3 = (xv).w;         \
        int i0 = 1, i1 = 2, i2 = 4, i3 = 8;   /* 1 << original index */   \
        /* stable sorting network (strict >): (0,1)(2,3)(0,2)(1,3)(1,2) */\
        if (a0 > a1) { float t=a0;a0=a1;a1=t; int u=i0;i0=i1;i1=u; }      \
        if (a2 > a3) { float t=a2;a2=a3;a3=t; int u=i2;i2=i3;i3=u; }      \
        if (a0 > a2) { float t=a0;a0=a2;a2=t; int u=i0;i0=i2;i2=u; }      \
        if (a1 > a3) { float t=a1;a1=a3;a3=t; int u=i1;i1=i3;i3=u; }      \
        if (a1 > a2) { float t=a1;a1=a2;a2=t; int u=i1;i1=i2;i2=u; }      \
        const float c0 = a0;                                              \
        const float c1 = a1 - a0;                                         \
        const float c2 = a2 - a1;                                         \
        const float c3 = a3 - a2;                                         \
        const int e3 = i3;                                                \
        const int e2 = e3 | i2;                                           \
        const int e1 = e2 | i1;                                           \
        const unsigned int s1 = (unsigned int)(m >> (e1 << 2));           \
        const unsigned int s2 = (unsigned int)(m >> (e2 << 2));           \
        const unsigned int s3 = (unsigned int)(m >> (e3 << 2));           \
        f4 r;                                                             \
        r.x = c0 + c1 * (float)( s1       & 1)                            \
                 + c2 * (float)( s2       & 1)                            \
                 + c3 * (float)( s3       & 1);                           \
        r.y = c0 + c1 * (float)((s1 >> 1) & 1)                            \
                 + c2 * (float)((s2 >> 1) & 1)                            \
                 + c3 * (float)((s3 >> 1) & 1);                           \
        r.z = c0 + c1 * (float)((s1 >> 2) & 1)                            \
                 + c2 * (float)((s2 >> 2) & 1)                            \
                 + c3 * (float)((s3 >> 2) & 1);                           \
        r.w = c0 + c1 * (float)((s1 >> 3) & 1)                            \
                 + c2 * (float)((s2 >> 3) & 1)                            \
                 + c3 * (float)((s3 >> 3) & 1);                           \
        __builtin_nontemporal_store(r, &O4[(off)]);                       \
    } while (0)

    PROCESS(x0, base);
    PROCESS(x1, base + GROUPS);
    PROCESS(x2, base + 2 * (size_t)GROUPS);
    PROCESS(x3, base + 3 * (size_t)GROUPS);
#undef PROCESS
}

extern "C" void kernel_launch(void* const* d_in, const int* in_sizes, int n_in,
                              void* d_out, int out_size, void* d_ws, size_t ws_size,
                              hipStream_t stream) {
    const float* X      = (const float*)d_in[0];
    const float* params = (const float*)d_in[1];
    float* out          = (float*)d_out;
    unsigned long long* masks = (unsigned long long*)d_ws;  // 2 KiB scratch

    build_masks_kernel<<<1, 256, 0, stream>>>(params, masks);
    mono_act_kernel<<<NBLOCKS, BLOCK_T, 0, stream>>>(X, masks, out);
}